// Round 2
// baseline (437.049 us; speedup 1.0000x reference)
//
#include <hip/hip_runtime.h>

#define B_ 64
#define T_ 256
#define DIN_ 1024
#define DOUT_ 1024

typedef int v4i  __attribute__((ext_vector_type(4)));
typedef int v16i __attribute__((ext_vector_type(16)));

#define PRE_BYTES 134217728ULL   // 256*1024*64*8
#define XS_BYTES  83886080ULL    // 5*256*32*2*1024
#define WSL_BYTES 5242880ULL     // 5*32*32*1024
#define SPM_BYTES 2097152ULL     // 256*1024*8

// async 16B/lane global->LDS DMA: per-lane global src, wave-uniform LDS base,
// lane i lands at ldsbase + i*16.
__device__ __forceinline__ void async_copy16(const void* g, void* l) {
    __builtin_amdgcn_global_load_lds(
        (const __attribute__((address_space(1))) void*)g,
        (__attribute__((address_space(3))) void*)l, 16, 0, 0);
}

// -----------------------------------------------------------------------------
// Split x into 5 signed-i8 slices, fixed scale 2^3, MFMA A-frag chunk order:
// chunk(s,t,kt,mt) = 1KB, byte = lane*16+j, lane = kh*32+m,
// element = x[b=mt*32+m][t][kt*32+kh*16+j]. 5 slices = 34 bits >= fp32's 24;
// residual <= 2^-32 absolute.
// -----------------------------------------------------------------------------
__global__ __launch_bounds__(256) void snn_split_x(
    const float* __restrict__ x, char* __restrict__ xs)
{
    const int W    = blockIdx.x * 4 + (threadIdx.x >> 6);   // 0..16383
    const int lane = threadIdx.x & 63;
    const int mt = W & 1, kt = (W >> 1) & 31, t0 = W >> 6;
    const int m = lane & 31, kh = lane >> 5;
    const int b = mt * 32 + m;

    const float* src = x + ((size_t)b * T_ + t0) * DIN_ + kt * 32 + kh * 16;
    float f[16];
    *(float4*)(f)      = *(const float4*)(src);
    *(float4*)(f + 4)  = *(const float4*)(src + 4);
    *(float4*)(f + 8)  = *(const float4*)(src + 8);
    *(float4*)(f + 12) = *(const float4*)(src + 12);

    unsigned pk[5][4];
#pragma unroll
    for (int s = 0; s < 5; ++s)
        pk[s][0] = pk[s][1] = pk[s][2] = pk[s][3] = 0u;
#pragma unroll
    for (int j = 0; j < 16; ++j) {
        float v = f[j] * 0.125f;                 // / 2^3 (exact)
#pragma unroll
        for (int s = 0; s < 5; ++s) {
            const float ml = (s == 0) ? 64.f : 128.f;
            const float sv = __builtin_rintf(v * ml);
            v = v * ml - sv;                     // exact residual
            const int iv = (int)sv;
            pk[s][j >> 2] |= ((unsigned)iv & 0xffu) << ((j & 3) * 8);
        }
    }
#pragma unroll
    for (int s = 0; s < 5; ++s) {
        char* dst = xs + (size_t)(((s * 256 + t0) * 32 + kt) * 2 + mt) * 1024
                       + lane * 16;
        *(uint4*)dst = make_uint4(pk[s][0], pk[s][1], pk[s][2], pk[s][3]);
    }
}

// -----------------------------------------------------------------------------
// Split W into 5 i8 slices, fixed scale 2^-2, B-frag chunk order:
// chunk(s,ot,kt) = 1KB, element = W[o=ot*32+n][kt*32+kh*16+j].
// -----------------------------------------------------------------------------
__global__ __launch_bounds__(256) void snn_split_w(
    const float* __restrict__ Wt, char* __restrict__ wsl)
{
    const int W    = blockIdx.x * 4 + (threadIdx.x >> 6);   // 0..1023
    const int lane = threadIdx.x & 63;
    const int kt = W & 31, ot = W >> 5;
    const int n = lane & 31, kh = lane >> 5;
    const int o = ot * 32 + n;

    const float* src = Wt + (size_t)o * DIN_ + kt * 32 + kh * 16;
    float f[16];
    *(float4*)(f)      = *(const float4*)(src);
    *(float4*)(f + 4)  = *(const float4*)(src + 4);
    *(float4*)(f + 8)  = *(const float4*)(src + 8);
    *(float4*)(f + 12) = *(const float4*)(src + 12);

    unsigned pk[5][4];
#pragma unroll
    for (int s = 0; s < 5; ++s)
        pk[s][0] = pk[s][1] = pk[s][2] = pk[s][3] = 0u;
#pragma unroll
    for (int j = 0; j < 16; ++j) {
        float v = f[j] * 4.0f;                   // / 2^-2 (exact)
#pragma unroll
        for (int s = 0; s < 5; ++s) {
            const float ml = (s == 0) ? 64.f : 128.f;
            const float sv = __builtin_rintf(v * ml);
            v = v * ml - sv;
            const int iv = (int)sv;
            pk[s][j >> 2] |= ((unsigned)iv & 0xffu) << ((j & 3) * 8);
        }
    }
#pragma unroll
    for (int s = 0; s < 5; ++s) {
        char* dst = wsl + (size_t)((s * 32 + ot) * 32 + kt) * 1024 + lane * 16;
        *(uint4*)dst = make_uint4(pk[s][0], pk[s][1], pk[s][2], pk[s][3]);
    }
}

// -----------------------------------------------------------------------------
// GEMM via i8 MFMA. KEY CONSTRAINT (round-0/1 post-mortem): acc registers set
// occupancy. 160-reg acc (2 ot/wave) -> 272 regs/wave -> 1 wave/SIMD -> zero
// TLP -> LDS/load latency serializes with MFMA (48%/38% MfmaUtil). This
// version: 64b x 64o block, 4 waves, ONE 32x32 ot per wave -> acc = 80 regs,
// total ~165 -> 3 waves/SIMD (enforced by __launch_bounds__(256,3)), ~3
// independent blocks/CU whose barriers don't align -> cross-block overlap.
//   A: register-direct from xs (fragment order), one-kt-ahead prefetch into
//      named aN regs (static indexing only). 2 waves share each A chunk (L1).
//   B: LDS double-buffer via global_load_lds (2x10KB), staged by waves 0,1.
// Grid 4096 = t0*16 + oc; oc%8 == XCD -> 640 KB B-slice L2-resident per XCD.
// LDS traffic: 12 waves*5KB reads + 30KB DMA per CU-kt ~ 43% of MFMA cycles.
// 5 slices, 15 exact triangular pair-MFMAs into i32 accs -> bit-exact.
// -----------------------------------------------------------------------------
__global__ __launch_bounds__(256, 3) void snn_gemm_i8(
    const char* __restrict__ xs, const char* __restrict__ wsl,
    const float* __restrict__ bias, double* __restrict__ pre)
{
    __shared__ __align__(16) char lds[2][10 * 1024];
    const int t0 = blockIdx.x >> 4;
    const int oc = blockIdx.x & 15;          // oc%8 == XCD under round-robin
    const int tid = threadIdx.x;
    const int lane = tid & 63;
    const int ws = __builtin_amdgcn_readfirstlane(tid >> 6);   // 0..3
    const int wm = ws >> 1;                  // b-half (A chunk) of this wave
    const int wo = ws & 1;                   // local ot of this wave
    const int lo = lane * 16;

    v16i acc[5];
#pragma unroll
    for (int g = 0; g < 5; ++g)
#pragma unroll
        for (int r = 0; r < 16; ++r) acc[g][r] = 0;

    // A fragments: per-lane global addr, chunk + s*16MB + kt*2048
    const char* ab = xs + (size_t)(t0 * 64 + wm) * 1024 + lo;
    // B staging source (waves 0,1): ot = oc*2 + ws
    const char* sg = wsl + (size_t)((oc * 2 + ws) * 32) * 1024 + lo;

    v4i aC[5], aN[5];
#pragma unroll
    for (int s = 0; s < 5; ++s)
        aC[s] = *(const v4i*)(ab + (size_t)s * 16777216);
    if (ws < 2) {
#pragma unroll
        for (int s = 0; s < 5; ++s)
            async_copy16(sg + (size_t)s * 1048576, &lds[0][(ws * 5 + s) * 1024]);
    }
    __syncthreads();

    for (int kt = 0; kt < 32; ++kt) {
        if (kt + 1 < 32) {
            const size_t ko = (size_t)(kt + 1);
#pragma unroll
            for (int s = 0; s < 5; ++s)
                aN[s] = *(const v4i*)(ab + (size_t)s * 16777216 + ko * 2048);
            if (ws < 2) {
                char* buf = lds[(kt + 1) & 1];
#pragma unroll
                for (int s = 0; s < 5; ++s)
                    async_copy16(sg + (size_t)s * 1048576 + ko * 1024,
                                 &buf[(ws * 5 + s) * 1024]);
            }
        }
        const char* cbuf = lds[kt & 1];
        v4i b[5];
#pragma unroll
        for (int s = 0; s < 5; ++s)
            b[s] = *(const v4i*)(cbuf + (wo * 5 + s) * 1024 + lo);

        __builtin_amdgcn_s_setprio(1);
#pragma unroll
        for (int i = 0; i < 5; ++i) {
#pragma unroll
            for (int j = 0; j < 5 - i; ++j)
                acc[i + j] = __builtin_amdgcn_mfma_i32_32x32x32_i8(
                    aC[i], b[j], acc[i + j], 0, 0, 0);
        }
        __builtin_amdgcn_s_setprio(0);
        __syncthreads();   // drains vmcnt (aN + next stage landed during MFMAs)
        if (kt + 1 < 32) {
#pragma unroll
            for (int s = 0; s < 5; ++s) aC[s] = aN[s];
        }
    }

    // epilogue: D layout col=lane&31 (o), row=(r&3)+8*(r>>2)+4*(lane>>5) (b)
    const int n = lane & 31, lh = lane >> 5;
    const int o = oc * 64 + wo * 32 + n;
    const double bv = (double)bias[o];
    double* dst = pre + ((size_t)t0 * DOUT_ + o) * 64 + wm * 32;
#pragma unroll
    for (int r = 0; r < 16; ++r) {
        const int row = (r & 3) + 8 * (r >> 2) + 4 * lh;
        double v = (double)acc[4][r];
        v = v * 0.0078125 + (double)acc[3][r];
        v = v * 0.0078125 + (double)acc[2][r];
        v = v * 0.0078125 + (double)acc[1][r];
        v = v * 0.0078125 + (double)acc[0][r];
        dst[row] = v * 0x1p-11 + bv;             // 2^{3-2-12}
    }
}

// -----------------------------------------------------------------------------
// Fallback GEMM (round-8 proven fp64-VALU path), used when ws is small.
// -----------------------------------------------------------------------------
__global__ __launch_bounds__(256, 2) void snn_gemm_fb(
    const float* __restrict__ x, const float* __restrict__ W,
    const float* __restrict__ bias, double* __restrict__ pre)
{
    __shared__ float smem[2][8 * 72 + 8 * 256];
    const int t0 = blockIdx.x & 255;
    const int o0 = blockIdx.x >> 8;
    const int tid = threadIdx.x;
    const int to = tid & 31;
    const int tb = tid >> 5;

    double acc[8][8];
#pragma unroll
    for (int i = 0; i < 8; ++i)
#pragma unroll
        for (int j = 0; j < 8; ++j) acc[i][j] = 0.0;

    const int arow = tid >> 2;
    const int ak2  = (tid & 3) * 2;
    const float* xg = x + (size_t)(t0 + 256 * arow) * DIN_ + ak2;
    const float* wg = W + (size_t)(o0 * 256 + tid) * DIN_;

    float2 f2  = *(const float2*)(xg);
    float4 bq0 = *(const float4*)(wg);
    float4 bq1 = *(const float4*)(wg + 4);

    for (int kc = 0; kc < DIN_ / 8; ++kc) {
        float* base = smem[kc & 1];
        float (*AsF)[72]  = (float(*)[72])base;
        float (*BsF)[256] = (float(*)[256])(base + 8 * 72);
        AsF[ak2 + 0][arow] = f2.x;
        AsF[ak2 + 1][arow] = f2.y;
        BsF[0][tid] = bq0.x;  BsF[1][tid] = bq0.y;
        BsF[2][tid] = bq0.z;  BsF[3][tid] = bq0.w;
        BsF[4][tid] = bq1.x;  BsF[5][tid] = bq1.y;
        BsF[6][tid] = bq1.z;  BsF[7][tid] = bq1.w;
        __syncthreads();
        if (kc + 1 < DIN_ / 8) {
            f2  = *(const float2*)(xg + (kc + 1) * 8);
            bq0 = *(const float4*)(wg + (kc + 1) * 8);
            bq1 = *(const float4*)(wg + (kc + 1) * 8 + 4);
        }
#pragma unroll
        for (int k = 0; k < 8; ++k) {
            const float4 af0 = *(const float4*)&AsF[k][tb * 8];
            const float4 af1 = *(const float4*)&AsF[k][tb * 8 + 4];
            const float4 bf0 = *(const float4*)&BsF[k][to * 4];
            const float4 bf1 = *(const float4*)&BsF[k][128 + to * 4];
            double a[8], b[8];
            a[0] = (double)af0.x; a[1] = (double)af0.y;
            a[2] = (double)af0.z; a[3] = (double)af0.w;
            a[4] = (double)af1.x; a[5] = (double)af1.y;
            a[6] = (double)af1.z; a[7] = (double)af1.w;
            b[0] = (double)bf0.x; b[1] = (double)bf0.y;
            b[2] = (double)bf0.z; b[3] = (double)bf0.w;
            b[4] = (double)bf1.x; b[5] = (double)bf1.y;
            b[6] = (double)bf1.z; b[7] = (double)bf1.w;
#pragma unroll
            for (int i = 0; i < 8; ++i)
#pragma unroll
                for (int j = 0; j < 8; ++j)
                    acc[i][j] += a[i] * b[j];
        }
        __syncthreads();
    }

    double biasd[8];
#pragma unroll
    for (int j = 0; j < 8; ++j)
        biasd[j] = (double)bias[o0 * 256 + (j >> 2) * 128 + to * 4 + (j & 3)];
    double (*trans)[67] = (double(*)[67])smem[0];
    for (int c = 0; c < 16; ++c) {
        __syncthreads();
        const int j4  = c >> 3;
        const int tlo = (c & 7) * 4;
        if (to >= tlo && to < tlo + 4) {
#pragma unroll
            for (int p4 = 0; p4 < 4; ++p4) {
                const int r = (to - tlo) * 4 + p4;
                const int j = j4 * 4 + p4;
#pragma unroll
                for (int i = 0; i < 8; ++i)
                    trans[r][tb * 8 + i] = acc[i][j] + biasd[j];
            }
        }
        __syncthreads();
#pragma unroll
        for (int q = 0; q < 4; ++q) {
            const int idx = tid + 256 * q;
            const int b  = idx & 63;
            const int oc = idx >> 6;
            pre[(size_t)(t0 * DOUT_ + o0 * 256 + c * 16 + oc) * 64 + b] = trans[oc][b];
        }
    }
}

// -----------------------------------------------------------------------------
// Scan: one wave per o, lane = b. Batch-mean via ballot+popcount.
// Software-pipelined 16-deep load batches (two NAMED arrays -> registers,
// never runtime-indexed): batch t+16 issues before batch t's serial
// ballot-chain runs, hiding ~900 cyc HBM latency under ~800 cyc of compute.
// -----------------------------------------------------------------------------
#define SCAN_LOAD(PV, TB)                                                      \
    do {                                                                       \
        _Pragma("unroll")                                                      \
        for (int j = 0; j < 16; ++j)                                           \
            PV[j] = p[(size_t)((TB) + j) * (DOUT_ * 64)];                      \
    } while (0)

#define SCAN_STEP(PV, TB)                                                      \
    do {                                                                       \
        _Pragma("unroll")                                                      \
        for (int j = 0; j < 16; ++j) {                                         \
            mem += PV[j];                                                      \
            const bool s = (mem >= thr);                                       \
            const unsigned long long msk = __ballot(s);                        \
            thr += 0.05 * ((double)__popcll(msk) * (1.0 / 64.0) - 0.5);        \
            if (spM) {                                                         \
                if (lane == 0) spM[(size_t)((TB) + j) * DOUT_ + o] = msk;      \
            } else {                                                           \
                outD[(size_t)lane * (T_ * DOUT_) +                             \
                     (size_t)((TB) + j) * DOUT_ + o] = s ? 1.0f : 0.0f;        \
            }                                                                  \
            mem = s ? 0.0 : mem;                                               \
        }                                                                      \
    } while (0)

__global__ __launch_bounds__(256) void snn_scan(
    const double* __restrict__ pre, const float* __restrict__ thr_in,
    unsigned long long* __restrict__ spM, float* __restrict__ outD)
{
    const int wid  = (blockIdx.x * blockDim.x + threadIdx.x) >> 6;
    const int lane = threadIdx.x & 63;
    if (wid >= DOUT_) return;
    const int o = wid;

    double mem = 0.0;
    double thr = (double)thr_in[o];
    const double* p = pre + (size_t)o * 64 + lane;

    double pvA[16], pvB[16];
    SCAN_LOAD(pvA, 0);
    for (int t = 0; t < T_; t += 32) {
        if (t + 16 < T_) SCAN_LOAD(pvB, t + 16);
        SCAN_STEP(pvA, t);
        if (t + 32 < T_) SCAN_LOAD(pvA, t + 32);
        SCAN_STEP(pvB, t + 16);
    }
}

// -----------------------------------------------------------------------------
// Expand: thread = (t, o-group-of-4). Reads 4 masks (32B/lane contiguous),
// writes float4 per b (16B/lane, 1KB/wave contiguous stores).
// -----------------------------------------------------------------------------
__global__ __launch_bounds__(256) void snn_expand(
    const unsigned long long* __restrict__ spM, float* __restrict__ out)
{
    const int idx = blockIdx.x * 256 + threadIdx.x;  // 0..65535
    const int og = idx & 255;                        // o/4
    const int t  = idx >> 8;
    const unsigned long long* mp = spM + (size_t)t * DOUT_ + og * 4;
    const unsigned long long m0 = mp[0], m1 = mp[1], m2 = mp[2], m3 = mp[3];
    float* op = out + (size_t)t * DOUT_ + og * 4;
#pragma unroll
    for (int b = 0; b < 64; ++b) {
        float4 v;
        v.x = (float)((m0 >> b) & 1ULL);
        v.y = (float)((m1 >> b) & 1ULL);
        v.z = (float)((m2 >> b) & 1ULL);
        v.w = (float)((m3 >> b) & 1ULL);
        *(float4*)(op + (size_t)b * (T_ * DOUT_)) = v;
    }
}

extern "C" void kernel_launch(void* const* d_in, const int* in_sizes, int n_in,
                              void* d_out, int out_size, void* d_ws, size_t ws_size,
                              hipStream_t stream) {
    const float* x    = (const float*)d_in[0];   // [64][256][1024]
    const float* W    = (const float*)d_in[1];   // [1024][1024]
    const float* bias = (const float*)d_in[2];   // [1024]
    const float* thr  = (const float*)d_in[3];   // [1024]
    float* out = (float*)d_out;                  // [64][256][1024]

    double* pre = (double*)d_ws;
    const size_t need = PRE_BYTES + XS_BYTES + WSL_BYTES + SPM_BYTES;

    if (ws_size >= need) {
        char* xs  = (char*)d_ws + PRE_BYTES;
        char* wsl = xs + XS_BYTES;
        unsigned long long* spM = (unsigned long long*)(wsl + WSL_BYTES);
        snn_split_x<<<4096, 256, 0, stream>>>(x, xs);
        snn_split_w<<<256, 256, 0, stream>>>(W, wsl);
        snn_gemm_i8<<<4096, 256, 0, stream>>>(xs, wsl, bias, pre);
        snn_scan<<<256, 256, 0, stream>>>(pre, thr, spM, nullptr);
        snn_expand<<<256, 256, 0, stream>>>(spM, out);
    } else {
        const bool two_stage = (ws_size >= PRE_BYTES + SPM_BYTES);
        unsigned long long* spM =
            two_stage ? (unsigned long long*)((char*)d_ws + PRE_BYTES) : nullptr;
        snn_gemm_fb<<<1024, 256, 0, stream>>>(x, W, bias, pre);
        snn_scan<<<256, 256, 0, stream>>>(pre, thr, spM, two_stage ? nullptr : out);
        if (two_stage)
            snn_expand<<<256, 256, 0, stream>>>(spM, out);
    }
}

// Round 3
// 410.097 us; speedup vs baseline: 1.0657x; 1.0657x over previous
//
#include <hip/hip_runtime.h>

#define B_ 64
#define T_ 256
#define DIN_ 1024
#define DOUT_ 1024

typedef int v4i  __attribute__((ext_vector_type(4)));
typedef int v16i __attribute__((ext_vector_type(16)));

#define PRE_BYTES 134217728ULL   // 256*1024*64*8
#define XS_BYTES  83886080ULL    // 5*256*32*2*1024
#define WSL_BYTES 5242880ULL     // 5*32*32*1024
#define SPM_BYTES 2097152ULL     // 256*1024*8

// async 16B/lane global->LDS DMA: per-lane global src, wave-uniform LDS base,
// lane i lands at ldsbase + i*16.
__device__ __forceinline__ void async_copy16(const void* g, void* l) {
    __builtin_amdgcn_global_load_lds(
        (const __attribute__((address_space(1))) void*)g,
        (__attribute__((address_space(3))) void*)l, 16, 0, 0);
}

// -----------------------------------------------------------------------------
// Split x into 5 signed-i8 slices, fixed scale 2^3, MFMA A-frag chunk order:
// chunk(s,t,kt,mt) = 1KB, byte = lane*16+j, lane = kh*32+m,
// element = x[b=mt*32+m][t][kt*32+kh*16+j]. 5 slices = 34 bits >= fp32's 24;
// residual <= 2^-32 absolute.
// -----------------------------------------------------------------------------
__global__ __launch_bounds__(256) void snn_split_x(
    const float* __restrict__ x, char* __restrict__ xs)
{
    const int W    = blockIdx.x * 4 + (threadIdx.x >> 6);   // 0..16383
    const int lane = threadIdx.x & 63;
    const int mt = W & 1, kt = (W >> 1) & 31, t0 = W >> 6;
    const int m = lane & 31, kh = lane >> 5;
    const int b = mt * 32 + m;

    const float* src = x + ((size_t)b * T_ + t0) * DIN_ + kt * 32 + kh * 16;
    float f[16];
    *(float4*)(f)      = *(const float4*)(src);
    *(float4*)(f + 4)  = *(const float4*)(src + 4);
    *(float4*)(f + 8)  = *(const float4*)(src + 8);
    *(float4*)(f + 12) = *(const float4*)(src + 12);

    unsigned pk[5][4];
#pragma unroll
    for (int s = 0; s < 5; ++s)
        pk[s][0] = pk[s][1] = pk[s][2] = pk[s][3] = 0u;
#pragma unroll
    for (int j = 0; j < 16; ++j) {
        float v = f[j] * 0.125f;                 // / 2^3 (exact)
#pragma unroll
        for (int s = 0; s < 5; ++s) {
            const float ml = (s == 0) ? 64.f : 128.f;
            const float sv = __builtin_rintf(v * ml);
            v = v * ml - sv;                     // exact residual
            const int iv = (int)sv;
            pk[s][j >> 2] |= ((unsigned)iv & 0xffu) << ((j & 3) * 8);
        }
    }
#pragma unroll
    for (int s = 0; s < 5; ++s) {
        char* dst = xs + (size_t)(((s * 256 + t0) * 32 + kt) * 2 + mt) * 1024
                       + lane * 16;
        *(uint4*)dst = make_uint4(pk[s][0], pk[s][1], pk[s][2], pk[s][3]);
    }
}

// -----------------------------------------------------------------------------
// Split W into 5 i8 slices, fixed scale 2^-2, B-frag chunk order:
// chunk(s,ot,kt) = 1KB, element = W[o=ot*32+n][kt*32+kh*16+j].
// -----------------------------------------------------------------------------
__global__ __launch_bounds__(256) void snn_split_w(
    const float* __restrict__ Wt, char* __restrict__ wsl)
{
    const int W    = blockIdx.x * 4 + (threadIdx.x >> 6);   // 0..1023
    const int lane = threadIdx.x & 63;
    const int kt = W & 31, ot = W >> 5;
    const int n = lane & 31, kh = lane >> 5;
    const int o = ot * 32 + n;

    const float* src = Wt + (size_t)o * DIN_ + kt * 32 + kh * 16;
    float f[16];
    *(float4*)(f)      = *(const float4*)(src);
    *(float4*)(f + 4)  = *(const float4*)(src + 4);
    *(float4*)(f + 8)  = *(const float4*)(src + 8);
    *(float4*)(f + 12) = *(const float4*)(src + 12);

    unsigned pk[5][4];
#pragma unroll
    for (int s = 0; s < 5; ++s)
        pk[s][0] = pk[s][1] = pk[s][2] = pk[s][3] = 0u;
#pragma unroll
    for (int j = 0; j < 16; ++j) {
        float v = f[j] * 4.0f;                   // / 2^-2 (exact)
#pragma unroll
        for (int s = 0; s < 5; ++s) {
            const float ml = (s == 0) ? 64.f : 128.f;
            const float sv = __builtin_rintf(v * ml);
            v = v * ml - sv;
            const int iv = (int)sv;
            pk[s][j >> 2] |= ((unsigned)iv & 0xffu) << ((j & 3) * 8);
        }
    }
#pragma unroll
    for (int s = 0; s < 5; ++s) {
        char* dst = wsl + (size_t)((s * 32 + ot) * 32 + kt) * 1024 + lane * 16;
        *(uint4*)dst = make_uint4(pk[s][0], pk[s][1], pk[s][2], pk[s][3]);
    }
}

// -----------------------------------------------------------------------------
// GEMM via i8 MFMA — T3/T4 schedule (counted vmcnt, raw s_barrier, never
// drain to 0 in steady state). Post-mortem r0-r2: __syncthreads drains
// vmcnt(0) each kt -> fixed ~1000-cyc stall/interval regardless of occupancy.
// Structure: 64b x 64o block, 4 waves, 1 ot/wave (acc = 80 regs -> 3
// waves/SIMD under __launch_bounds__(256,3)).
//   A: LDS 3-buffer, issue-ahead-2, staged by waves 0,1 (5 chunks each).
//      At top of kt: vmcnt(5) -> batch kt complete, batch kt+1 in flight.
//      Cover = 2 intervals (~1500 cyc) > HBM latency (~900).
//   B: LDS 2-buffer, issue-ahead-1, staged by waves 2,3; vmcnt(0) but B is
//      L2-resident (640 KB/XCD via oc%8 pinning) ~300 cyc < 1-interval cover.
// Stage-issue sits immediately AFTER the barrier: last readers of the target
// buffer ran before that barrier -> race-free with a single barrier/kt.
// LDS 50 KB -> 3 blocks/CU; per-SIMD MFMA demand 3x550=1650 cyc/interval.
// 5 slices, 15 exact triangular pair-MFMAs into i32 accs -> bit-exact.
// -----------------------------------------------------------------------------
__global__ __launch_bounds__(256, 3) void snn_gemm_i8(
    const char* __restrict__ xs, const char* __restrict__ wsl,
    const float* __restrict__ bias, double* __restrict__ pre)
{
    __shared__ __align__(16) char ldsA[3][10 * 1024];
    __shared__ __align__(16) char ldsB[2][10 * 1024];
    const int t0 = blockIdx.x >> 4;
    const int oc = blockIdx.x & 15;          // oc%8 == XCD under round-robin
    const int tid = threadIdx.x;
    const int lane = tid & 63;
    const int ws = __builtin_amdgcn_readfirstlane(tid >> 6);   // 0..3
    const int wm = ws >> 1;                  // b-half (A chunk) of this wave
    const int wo = ws & 1;                   // local ot of this wave
    const int lo = lane * 16;

    v16i acc[5];
#pragma unroll
    for (int g = 0; g < 5; ++g)
#pragma unroll
        for (int r = 0; r < 16; ++r) acc[g][r] = 0;

    // staging sources (per-lane global addr = wave-uniform base + lane*16)
    // A-stagers (ws 0,1): chunk wm=ws; B-stagers (ws 2,3): chunk wo=ws-2.
    const char* sgA = xs  + (size_t)(t0 * 64 + ws) * 1024 + lo;          // ws<2
    const char* sgB = wsl + (size_t)((oc * 2 + (ws - 2)) * 32) * 1024 + lo;

    // prologue: A batches 0,1 -> bufs 0,1 ; B batch 0 -> buf 0
    if (ws < 2) {
#pragma unroll
        for (int s = 0; s < 5; ++s)
            async_copy16(sgA + (size_t)s * 16777216, &ldsA[0][(ws * 5 + s) * 1024]);
#pragma unroll
        for (int s = 0; s < 5; ++s)
            async_copy16(sgA + (size_t)s * 16777216 + 2048,
                         &ldsA[1][(ws * 5 + s) * 1024]);
    } else {
#pragma unroll
        for (int s = 0; s < 5; ++s)
            async_copy16(sgB + (size_t)s * 1048576,
                         &ldsB[0][((ws - 2) * 5 + s) * 1024]);
    }

    int rdA = 0;   // kt % 3
    int stA = 2;   // (kt+2) % 3
    for (int kt = 0; kt < 32; ++kt) {
        // counted waits: A-stagers leave batch kt+1 in flight; B-stagers and
        // tail drain. Ensures own batch kt landed BEFORE the barrier, so
        // after the barrier every wave sees buf[kt] staged.
        if (ws < 2) {
            if (kt < 31) asm volatile("s_waitcnt vmcnt(5)" ::: "memory");
            else         asm volatile("s_waitcnt vmcnt(0)" ::: "memory");
        } else {
            asm volatile("s_waitcnt vmcnt(0)" ::: "memory");
        }
        __builtin_amdgcn_s_barrier();
        asm volatile("" ::: "memory");

        // stage ahead (after barrier: previous readers of target buf done)
        if (ws < 2) {
            if (kt + 2 < 32) {
                const size_t ko = (size_t)(kt + 2) * 2048;
#pragma unroll
                for (int s = 0; s < 5; ++s)
                    async_copy16(sgA + (size_t)s * 16777216 + ko,
                                 &ldsA[stA][(ws * 5 + s) * 1024]);
            }
        } else {
            if (kt + 1 < 32) {
                const size_t ko = (size_t)(kt + 1) * 1024;
#pragma unroll
                for (int s = 0; s < 5; ++s)
                    async_copy16(sgB + (size_t)s * 1048576 + ko,
                                 &ldsB[(kt + 1) & 1][((ws - 2) * 5 + s) * 1024]);
            }
        }

        const char* bufA = ldsA[rdA];
        const char* bufB = ldsB[kt & 1];
        v4i a[5], b[5];
#pragma unroll
        for (int s = 0; s < 5; ++s)
            a[s] = *(const v4i*)(bufA + (wm * 5 + s) * 1024 + lo);
#pragma unroll
        for (int s = 0; s < 5; ++s)
            b[s] = *(const v4i*)(bufB + (wo * 5 + s) * 1024 + lo);

        __builtin_amdgcn_s_setprio(1);
#pragma unroll
        for (int i = 0; i < 5; ++i) {
#pragma unroll
            for (int j = 0; j < 5 - i; ++j)
                acc[i + j] = __builtin_amdgcn_mfma_i32_32x32x32_i8(
                    a[i], b[j], acc[i + j], 0, 0, 0);
        }
        __builtin_amdgcn_s_setprio(0);

        rdA = (rdA == 2) ? 0 : rdA + 1;
        stA = (stA == 2) ? 0 : stA + 1;
    }

    // epilogue: D layout col=lane&31 (o), row=(r&3)+8*(r>>2)+4*(lane>>5) (b)
    const int n = lane & 31, lh = lane >> 5;
    const int o = oc * 64 + wo * 32 + n;
    const double bv = (double)bias[o];
    double* dst = pre + ((size_t)t0 * DOUT_ + o) * 64 + wm * 32;
#pragma unroll
    for (int r = 0; r < 16; ++r) {
        const int row = (r & 3) + 8 * (r >> 2) + 4 * lh;
        double v = (double)acc[4][r];
        v = v * 0.0078125 + (double)acc[3][r];
        v = v * 0.0078125 + (double)acc[2][r];
        v = v * 0.0078125 + (double)acc[1][r];
        v = v * 0.0078125 + (double)acc[0][r];
        dst[row] = v * 0x1p-11 + bv;             // 2^{3-2-12}
    }
}

// -----------------------------------------------------------------------------
// Fallback GEMM (round-8 proven fp64-VALU path), used when ws is small.
// -----------------------------------------------------------------------------
__global__ __launch_bounds__(256, 2) void snn_gemm_fb(
    const float* __restrict__ x, const float* __restrict__ W,
    const float* __restrict__ bias, double* __restrict__ pre)
{
    __shared__ float smem[2][8 * 72 + 8 * 256];
    const int t0 = blockIdx.x & 255;
    const int o0 = blockIdx.x >> 8;
    const int tid = threadIdx.x;
    const int to = tid & 31;
    const int tb = tid >> 5;

    double acc[8][8];
#pragma unroll
    for (int i = 0; i < 8; ++i)
#pragma unroll
        for (int j = 0; j < 8; ++j) acc[i][j] = 0.0;

    const int arow = tid >> 2;
    const int ak2  = (tid & 3) * 2;
    const float* xg = x + (size_t)(t0 + 256 * arow) * DIN_ + ak2;
    const float* wg = W + (size_t)(o0 * 256 + tid) * DIN_;

    float2 f2  = *(const float2*)(xg);
    float4 bq0 = *(const float4*)(wg);
    float4 bq1 = *(const float4*)(wg + 4);

    for (int kc = 0; kc < DIN_ / 8; ++kc) {
        float* base = smem[kc & 1];
        float (*AsF)[72]  = (float(*)[72])base;
        float (*BsF)[256] = (float(*)[256])(base + 8 * 72);
        AsF[ak2 + 0][arow] = f2.x;
        AsF[ak2 + 1][arow] = f2.y;
        BsF[0][tid] = bq0.x;  BsF[1][tid] = bq0.y;
        BsF[2][tid] = bq0.z;  BsF[3][tid] = bq0.w;
        BsF[4][tid] = bq1.x;  BsF[5][tid] = bq1.y;
        BsF[6][tid] = bq1.z;  BsF[7][tid] = bq1.w;
        __syncthreads();
        if (kc + 1 < DIN_ / 8) {
            f2  = *(const float2*)(xg + (kc + 1) * 8);
            bq0 = *(const float4*)(wg + (kc + 1) * 8);
            bq1 = *(const float4*)(wg + (kc + 1) * 8 + 4);
        }
#pragma unroll
        for (int k = 0; k < 8; ++k) {
            const float4 af0 = *(const float4*)&AsF[k][tb * 8];
            const float4 af1 = *(const float4*)&AsF[k][tb * 8 + 4];
            const float4 bf0 = *(const float4*)&BsF[k][to * 4];
            const float4 bf1 = *(const float4*)&BsF[k][128 + to * 4];
            double a[8], b[8];
            a[0] = (double)af0.x; a[1] = (double)af0.y;
            a[2] = (double)af0.z; a[3] = (double)af0.w;
            a[4] = (double)af1.x; a[5] = (double)af1.y;
            a[6] = (double)af1.z; a[7] = (double)af1.w;
            b[0] = (double)bf0.x; b[1] = (double)bf0.y;
            b[2] = (double)bf0.z; b[3] = (double)bf0.w;
            b[4] = (double)bf1.x; b[5] = (double)bf1.y;
            b[6] = (double)bf1.z; b[7] = (double)bf1.w;
#pragma unroll
            for (int i = 0; i < 8; ++i)
#pragma unroll
                for (int j = 0; j < 8; ++j)
                    acc[i][j] += a[i] * b[j];
        }
        __syncthreads();
    }

    double biasd[8];
#pragma unroll
    for (int j = 0; j < 8; ++j)
        biasd[j] = (double)bias[o0 * 256 + (j >> 2) * 128 + to * 4 + (j & 3)];
    double (*trans)[67] = (double(*)[67])smem[0];
    for (int c = 0; c < 16; ++c) {
        __syncthreads();
        const int j4  = c >> 3;
        const int tlo = (c & 7) * 4;
        if (to >= tlo && to < tlo + 4) {
#pragma unroll
            for (int p4 = 0; p4 < 4; ++p4) {
                const int r = (to - tlo) * 4 + p4;
                const int j = j4 * 4 + p4;
#pragma unroll
                for (int i = 0; i < 8; ++i)
                    trans[r][tb * 8 + i] = acc[i][j] + biasd[j];
            }
        }
        __syncthreads();
#pragma unroll
        for (int q = 0; q < 4; ++q) {
            const int idx = tid + 256 * q;
            const int b  = idx & 63;
            const int oc = idx >> 6;
            pre[(size_t)(t0 * DOUT_ + o0 * 256 + c * 16 + oc) * 64 + b] = trans[oc][b];
        }
    }
}

// -----------------------------------------------------------------------------
// Scan: one wave per o, lane = b. Batch-mean via ballot+popcount.
// Software-pipelined 16-deep load batches (two NAMED arrays -> registers,
// never runtime-indexed): batch t+16 issues before batch t's serial
// ballot-chain runs, hiding ~900 cyc HBM latency under ~800 cyc of compute.
// -----------------------------------------------------------------------------
#define SCAN_LOAD(PV, TB)                                                      \
    do {                                                                       \
        _Pragma("unroll")                                                      \
        for (int j = 0; j < 16; ++j)                                           \
            PV[j] = p[(size_t)((TB) + j) * (DOUT_ * 64)];                      \
    } while (0)

#define SCAN_STEP(PV, TB)                                                      \
    do {                                                                       \
        _Pragma("unroll")                                                      \
        for (int j = 0; j < 16; ++j) {                                         \
            mem += PV[j];                                                      \
            const bool s = (mem >= thr);                                       \
            const unsigned long long msk = __ballot(s);                        \
            thr += 0.05 * ((double)__popcll(msk) * (1.0 / 64.0) - 0.5);        \
            if (spM) {                                                         \
                if (lane == 0) spM[(size_t)((TB) + j) * DOUT_ + o] = msk;      \
            } else {                                                           \
                outD[(size_t)lane * (T_ * DOUT_) +                             \
                     (size_t)((TB) + j) * DOUT_ + o] = s ? 1.0f : 0.0f;        \
            }                                                                  \
            mem = s ? 0.0 : mem;                                               \
        }                                                                      \
    } while (0)

__global__ __launch_bounds__(256) void snn_scan(
    const double* __restrict__ pre, const float* __restrict__ thr_in,
    unsigned long long* __restrict__ spM, float* __restrict__ outD)
{
    const int wid  = (blockIdx.x * blockDim.x + threadIdx.x) >> 6;
    const int lane = threadIdx.x & 63;
    if (wid >= DOUT_) return;
    const int o = wid;

    double mem = 0.0;
    double thr = (double)thr_in[o];
    const double* p = pre + (size_t)o * 64 + lane;

    double pvA[16], pvB[16];
    SCAN_LOAD(pvA, 0);
    for (int t = 0; t < T_; t += 32) {
        if (t + 16 < T_) SCAN_LOAD(pvB, t + 16);
        SCAN_STEP(pvA, t);
        if (t + 32 < T_) SCAN_LOAD(pvA, t + 32);
        SCAN_STEP(pvB, t + 16);
    }
}

// -----------------------------------------------------------------------------
// Expand: thread = (t, o-group-of-4). Reads 4 masks (32B/lane contiguous),
// writes float4 per b (16B/lane, 1KB/wave contiguous stores).
// -----------------------------------------------------------------------------
__global__ __launch_bounds__(256) void snn_expand(
    const unsigned long long* __restrict__ spM, float* __restrict__ out)
{
    const int idx = blockIdx.x * 256 + threadIdx.x;  // 0..65535
    const int og = idx & 255;                        // o/4
    const int t  = idx >> 8;
    const unsigned long long* mp = spM + (size_t)t * DOUT_ + og * 4;
    const unsigned long long m0 = mp[0], m1 = mp[1], m2 = mp[2], m3 = mp[3];
    float* op = out + (size_t)t * DOUT_ + og * 4;
#pragma unroll
    for (int b = 0; b < 64; ++b) {
        float4 v;
        v.x = (float)((m0 >> b) & 1ULL);
        v.y = (float)((m1 >> b) & 1ULL);
        v.z = (float)((m2 >> b) & 1ULL);
        v.w = (float)((m3 >> b) & 1ULL);
        *(float4*)(op + (size_t)b * (T_ * DOUT_)) = v;
    }
}

extern "C" void kernel_launch(void* const* d_in, const int* in_sizes, int n_in,
                              void* d_out, int out_size, void* d_ws, size_t ws_size,
                              hipStream_t stream) {
    const float* x    = (const float*)d_in[0];   // [64][256][1024]
    const float* W    = (const float*)d_in[1];   // [1024][1024]
    const float* bias = (const float*)d_in[2];   // [1024]
    const float* thr  = (const float*)d_in[3];   // [1024]
    float* out = (float*)d_out;                  // [64][256][1024]

    double* pre = (double*)d_ws;
    const size_t need = PRE_BYTES + XS_BYTES + WSL_BYTES + SPM_BYTES;

    if (ws_size >= need) {
        char* xs  = (char*)d_ws + PRE_BYTES;
        char* wsl = xs + XS_BYTES;
        unsigned long long* spM = (unsigned long long*)(wsl + WSL_BYTES);
        snn_split_x<<<4096, 256, 0, stream>>>(x, xs);
        snn_split_w<<<256, 256, 0, stream>>>(W, wsl);
        snn_gemm_i8<<<4096, 256, 0, stream>>>(xs, wsl, bias, pre);
        snn_scan<<<256, 256, 0, stream>>>(pre, thr, spM, nullptr);
        snn_expand<<<256, 256, 0, stream>>>(spM, out);
    } else {
        const bool two_stage = (ws_size >= PRE_BYTES + SPM_BYTES);
        unsigned long long* spM =
            two_stage ? (unsigned long long*)((char*)d_ws + PRE_BYTES) : nullptr;
        snn_gemm_fb<<<1024, 256, 0, stream>>>(x, W, bias, pre);
        snn_scan<<<256, 256, 0, stream>>>(pre, thr, spM, two_stage ? nullptr : out);
        if (two_stage)
            snn_expand<<<256, 256, 0, stream>>>(spM, out);
    }
}

// Round 4
// 391.070 us; speedup vs baseline: 1.1176x; 1.0487x over previous
//
#include <hip/hip_runtime.h>

#define B_ 64
#define T_ 256
#define DIN_ 1024
#define DOUT_ 1024

typedef int v4i  __attribute__((ext_vector_type(4)));
typedef int v16i __attribute__((ext_vector_type(16)));

#define PRE_BYTES 134217728ULL   // 256*1024*64*8
#define XS_BYTES  83886080ULL    // 5*256*32*2*1024
#define WSL_BYTES 5242880ULL     // 5*32*32*1024
#define SPM_BYTES 2097152ULL     // 256*1024*8

// async 16B/lane global->LDS DMA: per-lane global src, wave-uniform LDS base,
// lane i lands at ldsbase + i*16.
__device__ __forceinline__ void async_copy16(const void* g, void* l) {
    __builtin_amdgcn_global_load_lds(
        (const __attribute__((address_space(1))) void*)g,
        (__attribute__((address_space(3))) void*)l, 16, 0, 0);
}

// -----------------------------------------------------------------------------
// Split x into 5 signed-i8 slices, fixed scale 2^3, MFMA A-frag chunk order:
// chunk(s,t,kt,mt) = 1KB, byte = lane*16+j, lane = kh*32+m,
// element = x[b=mt*32+m][t][kt*32+kh*16+j]. 5 slices = 34 bits >= fp32's 24;
// residual <= 2^-32 absolute.
// -----------------------------------------------------------------------------
__global__ __launch_bounds__(256) void snn_split_x(
    const float* __restrict__ x, char* __restrict__ xs)
{
    const int W    = blockIdx.x * 4 + (threadIdx.x >> 6);   // 0..16383
    const int lane = threadIdx.x & 63;
    const int mt = W & 1, kt = (W >> 1) & 31, t0 = W >> 6;
    const int m = lane & 31, kh = lane >> 5;
    const int b = mt * 32 + m;

    const float* src = x + ((size_t)b * T_ + t0) * DIN_ + kt * 32 + kh * 16;
    float f[16];
    *(float4*)(f)      = *(const float4*)(src);
    *(float4*)(f + 4)  = *(const float4*)(src + 4);
    *(float4*)(f + 8)  = *(const float4*)(src + 8);
    *(float4*)(f + 12) = *(const float4*)(src + 12);

    unsigned pk[5][4];
#pragma unroll
    for (int s = 0; s < 5; ++s)
        pk[s][0] = pk[s][1] = pk[s][2] = pk[s][3] = 0u;
#pragma unroll
    for (int j = 0; j < 16; ++j) {
        float v = f[j] * 0.125f;                 // / 2^3 (exact)
#pragma unroll
        for (int s = 0; s < 5; ++s) {
            const float ml = (s == 0) ? 64.f : 128.f;
            const float sv = __builtin_rintf(v * ml);
            v = v * ml - sv;                     // exact residual
            const int iv = (int)sv;
            pk[s][j >> 2] |= ((unsigned)iv & 0xffu) << ((j & 3) * 8);
        }
    }
#pragma unroll
    for (int s = 0; s < 5; ++s) {
        char* dst = xs + (size_t)(((s * 256 + t0) * 32 + kt) * 2 + mt) * 1024
                       + lane * 16;
        *(uint4*)dst = make_uint4(pk[s][0], pk[s][1], pk[s][2], pk[s][3]);
    }
}

// -----------------------------------------------------------------------------
// Split W into 5 i8 slices, fixed scale 2^-2, B-frag chunk order:
// chunk(s,ot,kt) = 1KB, element = W[o=ot*32+n][kt*32+kh*16+j].
// -----------------------------------------------------------------------------
__global__ __launch_bounds__(256) void snn_split_w(
    const float* __restrict__ Wt, char* __restrict__ wsl)
{
    const int W    = blockIdx.x * 4 + (threadIdx.x >> 6);   // 0..1023
    const int lane = threadIdx.x & 63;
    const int kt = W & 31, ot = W >> 5;
    const int n = lane & 31, kh = lane >> 5;
    const int o = ot * 32 + n;

    const float* src = Wt + (size_t)o * DIN_ + kt * 32 + kh * 16;
    float f[16];
    *(float4*)(f)      = *(const float4*)(src);
    *(float4*)(f + 4)  = *(const float4*)(src + 4);
    *(float4*)(f + 8)  = *(const float4*)(src + 8);
    *(float4*)(f + 12) = *(const float4*)(src + 12);

    unsigned pk[5][4];
#pragma unroll
    for (int s = 0; s < 5; ++s)
        pk[s][0] = pk[s][1] = pk[s][2] = pk[s][3] = 0u;
#pragma unroll
    for (int j = 0; j < 16; ++j) {
        float v = f[j] * 4.0f;                   // / 2^-2 (exact)
#pragma unroll
        for (int s = 0; s < 5; ++s) {
            const float ml = (s == 0) ? 64.f : 128.f;
            const float sv = __builtin_rintf(v * ml);
            v = v * ml - sv;
            const int iv = (int)sv;
            pk[s][j >> 2] |= ((unsigned)iv & 0xffu) << ((j & 3) * 8);
        }
    }
#pragma unroll
    for (int s = 0; s < 5; ++s) {
        char* dst = wsl + (size_t)((s * 32 + ot) * 32 + kt) * 1024 + lane * 16;
        *(uint4*)dst = make_uint4(pk[s][0], pk[s][1], pk[s][2], pk[s][3]);
    }
}

// -----------------------------------------------------------------------------
// GEMM via i8 MFMA — register-pipelined T3/T4 schedule.
// r0-r3 post-mortem: MfmaUtil pinned ~47% because every interval's critical
// path is barrier -> ds_read (latency, contended) -> MFMA, resynchronized by
// the per-kt barrier. Fix: ds_read kt+1's fragments into the OTHER reg set
// DURING kt's MFMAs (ping-pong aP/bP <-> aQ/bQ, all statically indexed), so
// LDS latency sits in the MFMA shadow and the interval is pure issue.
//   - 4-deep LDS buffers A and B (4x10KB each = 80KB -> exactly 2 blocks/CU).
//   - issue-ahead-3: DMA batch kt+3 issued during interval kt.
//   - top-of-interval wait vmcnt(5): batch kt+1 complete (issued 2 intervals
//     ago -> free), batch kt+2 rides through the barrier. Tail: vmcnt(0).
//   - buffer lifetime: batch j written @ j-3, read @ j-1, overwritten @ j+1
//     -> one barrier of slack. Single barrier per interval.
// All 4 waves stage 5 DMAs/interval (ws 0,1 -> A chunks; ws 2,3 -> B chunks).
// Regs ~185 (80 acc + 80 operand) -> 2 waves/SIMD; MFMA demand 1100 cyc vs
// LDS pipe 1280 cyc per interval -> ~85% ideal MfmaUtil.
// 5 slices, 15 exact triangular pair-MFMAs into i32 accs -> bit-exact.
// -----------------------------------------------------------------------------
#define GEMM_INTERVAL(KT, RA_CUR, RB_CUR, RA_NXT, RB_NXT)                      \
    do {                                                                       \
        if ((KT) < 30) asm volatile("s_waitcnt vmcnt(5)" ::: "memory");        \
        else           asm volatile("s_waitcnt vmcnt(0)" ::: "memory");        \
        __builtin_amdgcn_s_barrier();                                          \
        asm volatile("" ::: "memory");                                         \
        if ((KT) + 3 < 32) {                                                   \
            const int jb = (KT) + 3;                                           \
            if (ws < 2) {                                                      \
                _Pragma("unroll")                                              \
                for (int s = 0; s < 5; ++s)                                    \
                    async_copy16(sgA + (size_t)s * 16777216 + (size_t)jb * 2048,\
                                 &ldsA[jb & 3][(ws * 5 + s) * 1024]);          \
            } else {                                                           \
                _Pragma("unroll")                                              \
                for (int s = 0; s < 5; ++s)                                    \
                    async_copy16(sgB + (size_t)s * 1048576 + (size_t)jb * 1024,\
                                 &ldsB[jb & 3][((ws - 2) * 5 + s) * 1024]);    \
            }                                                                  \
        }                                                                      \
        if ((KT) + 1 < 32) {                                                   \
            const char* nA = ldsA[((KT) + 1) & 3];                             \
            const char* nB = ldsB[((KT) + 1) & 3];                             \
            _Pragma("unroll")                                                  \
            for (int s = 0; s < 5; ++s) {                                      \
                RA_NXT[s] = *(const v4i*)(nA + (wm * 5 + s) * 1024 + lo);      \
                RB_NXT[s] = *(const v4i*)(nB + (wo * 5 + s) * 1024 + lo);      \
            }                                                                  \
        }                                                                      \
        __builtin_amdgcn_s_setprio(1);                                        \
        _Pragma("unroll")                                                      \
        for (int i = 0; i < 5; ++i) {                                          \
            _Pragma("unroll")                                                  \
            for (int j = 0; j < 5 - i; ++j)                                    \
                acc[i + j] = __builtin_amdgcn_mfma_i32_32x32x32_i8(            \
                    RA_CUR[i], RB_CUR[j], acc[i + j], 0, 0, 0);                \
        }                                                                      \
        __builtin_amdgcn_s_setprio(0);                                        \
    } while (0)

__global__ __launch_bounds__(256, 2) void snn_gemm_i8(
    const char* __restrict__ xs, const char* __restrict__ wsl,
    const float* __restrict__ bias, double* __restrict__ pre)
{
    __shared__ __align__(16) char ldsA[4][10 * 1024];
    __shared__ __align__(16) char ldsB[4][10 * 1024];
    const int t0 = blockIdx.x >> 4;
    const int oc = blockIdx.x & 15;          // oc%8 == XCD under round-robin
    const int tid = threadIdx.x;
    const int lane = tid & 63;
    const int ws = __builtin_amdgcn_readfirstlane(tid >> 6);   // 0..3
    const int wm = ws >> 1;                  // b-half (A chunk) this wave uses
    const int wo = ws & 1;                   // local ot (B chunk) this wave uses
    const int lo = lane * 16;

    v16i acc[5];
#pragma unroll
    for (int g = 0; g < 5; ++g)
#pragma unroll
        for (int r = 0; r < 16; ++r) acc[g][r] = 0;

    // staging sources (per-lane global addr = wave-uniform base + lane*16)
    const char* sgA = xs  + (size_t)(t0 * 64 + ws) * 1024 + lo;          // ws<2
    const char* sgB = wsl + (size_t)((oc * 2 + (ws - 2)) * 32) * 1024 + lo;

    // prologue: issue batches 0,1,2 (15 DMAs/wave, oldest-first)
    if (ws < 2) {
#pragma unroll
        for (int j = 0; j < 3; ++j)
#pragma unroll
            for (int s = 0; s < 5; ++s)
                async_copy16(sgA + (size_t)s * 16777216 + (size_t)j * 2048,
                             &ldsA[j][(ws * 5 + s) * 1024]);
    } else {
#pragma unroll
        for (int j = 0; j < 3; ++j)
#pragma unroll
            for (int s = 0; s < 5; ++s)
                async_copy16(sgB + (size_t)s * 1048576 + (size_t)j * 1024,
                             &ldsB[j][((ws - 2) * 5 + s) * 1024]);
    }
    asm volatile("s_waitcnt vmcnt(10)" ::: "memory");   // batch 0 complete
    __builtin_amdgcn_s_barrier();
    asm volatile("" ::: "memory");

    v4i aP[5], bP[5], aQ[5], bQ[5];
#pragma unroll
    for (int s = 0; s < 5; ++s) {
        aP[s] = *(const v4i*)(&ldsA[0][0] + (wm * 5 + s) * 1024 + lo);
        bP[s] = *(const v4i*)(&ldsB[0][0] + (wo * 5 + s) * 1024 + lo);
    }

    for (int ks = 0; ks < 16; ++ks) {
        const int kt = 2 * ks;
        GEMM_INTERVAL(kt,     aP, bP, aQ, bQ);
        GEMM_INTERVAL(kt + 1, aQ, bQ, aP, bP);
    }

    // epilogue: D layout col=lane&31 (o), row=(r&3)+8*(r>>2)+4*(lane>>5) (b)
    const int n = lane & 31, lh = lane >> 5;
    const int o = oc * 64 + wo * 32 + n;
    const double bv = (double)bias[o];
    double* dst = pre + ((size_t)t0 * DOUT_ + o) * 64 + wm * 32;
#pragma unroll
    for (int r = 0; r < 16; ++r) {
        const int row = (r & 3) + 8 * (r >> 2) + 4 * lh;
        double v = (double)acc[4][r];
        v = v * 0.0078125 + (double)acc[3][r];
        v = v * 0.0078125 + (double)acc[2][r];
        v = v * 0.0078125 + (double)acc[1][r];
        v = v * 0.0078125 + (double)acc[0][r];
        dst[row] = v * 0x1p-11 + bv;             // 2^{3-2-12}
    }
}

// -----------------------------------------------------------------------------
// Fallback GEMM (round-8 proven fp64-VALU path), used when ws is small.
// -----------------------------------------------------------------------------
__global__ __launch_bounds__(256, 2) void snn_gemm_fb(
    const float* __restrict__ x, const float* __restrict__ W,
    const float* __restrict__ bias, double* __restrict__ pre)
{
    __shared__ float smem[2][8 * 72 + 8 * 256];
    const int t0 = blockIdx.x & 255;
    const int o0 = blockIdx.x >> 8;
    const int tid = threadIdx.x;
    const int to = tid & 31;
    const int tb = tid >> 5;

    double acc[8][8];
#pragma unroll
    for (int i = 0; i < 8; ++i)
#pragma unroll
        for (int j = 0; j < 8; ++j) acc[i][j] = 0.0;

    const int arow = tid >> 2;
    const int ak2  = (tid & 3) * 2;
    const float* xg = x + (size_t)(t0 + 256 * arow) * DIN_ + ak2;
    const float* wg = W + (size_t)(o0 * 256 + tid) * DIN_;

    float2 f2  = *(const float2*)(xg);
    float4 bq0 = *(const float4*)(wg);
    float4 bq1 = *(const float4*)(wg + 4);

    for (int kc = 0; kc < DIN_ / 8; ++kc) {
        float* base = smem[kc & 1];
        float (*AsF)[72]  = (float(*)[72])base;
        float (*BsF)[256] = (float(*)[256])(base + 8 * 72);
        AsF[ak2 + 0][arow] = f2.x;
        AsF[ak2 + 1][arow] = f2.y;
        BsF[0][tid] = bq0.x;  BsF[1][tid] = bq0.y;
        BsF[2][tid] = bq0.z;  BsF[3][tid] = bq0.w;
        BsF[4][tid] = bq1.x;  BsF[5][tid] = bq1.y;
        BsF[6][tid] = bq1.z;  BsF[7][tid] = bq1.w;
        __syncthreads();
        if (kc + 1 < DIN_ / 8) {
            f2  = *(const float2*)(xg + (kc + 1) * 8);
            bq0 = *(const float4*)(wg + (kc + 1) * 8);
            bq1 = *(const float4*)(wg + (kc + 1) * 8 + 4);
        }
#pragma unroll
        for (int k = 0; k < 8; ++k) {
            const float4 af0 = *(const float4*)&AsF[k][tb * 8];
            const float4 af1 = *(const float4*)&AsF[k][tb * 8 + 4];
            const float4 bf0 = *(const float4*)&BsF[k][to * 4];
            const float4 bf1 = *(const float4*)&BsF[k][128 + to * 4];
            double a[8], b[8];
            a[0] = (double)af0.x; a[1] = (double)af0.y;
            a[2] = (double)af0.z; a[3] = (double)af0.w;
            a[4] = (double)af1.x; a[5] = (double)af1.y;
            a[6] = (double)af1.z; a[7] = (double)af1.w;
            b[0] = (double)bf0.x; b[1] = (double)bf0.y;
            b[2] = (double)bf0.z; b[3] = (double)bf0.w;
            b[4] = (double)bf1.x; b[5] = (double)bf1.y;
            b[6] = (double)bf1.z; b[7] = (double)bf1.w;
#pragma unroll
            for (int i = 0; i < 8; ++i)
#pragma unroll
                for (int j = 0; j < 8; ++j)
                    acc[i][j] += a[i] * b[j];
        }
        __syncthreads();
    }

    double biasd[8];
#pragma unroll
    for (int j = 0; j < 8; ++j)
        biasd[j] = (double)bias[o0 * 256 + (j >> 2) * 128 + to * 4 + (j & 3)];
    double (*trans)[67] = (double(*)[67])smem[0];
    for (int c = 0; c < 16; ++c) {
        __syncthreads();
        const int j4  = c >> 3;
        const int tlo = (c & 7) * 4;
        if (to >= tlo && to < tlo + 4) {
#pragma unroll
            for (int p4 = 0; p4 < 4; ++p4) {
                const int r = (to - tlo) * 4 + p4;
                const int j = j4 * 4 + p4;
#pragma unroll
                for (int i = 0; i < 8; ++i)
                    trans[r][tb * 8 + i] = acc[i][j] + biasd[j];
            }
        }
        __syncthreads();
#pragma unroll
        for (int q = 0; q < 4; ++q) {
            const int idx = tid + 256 * q;
            const int b  = idx & 63;
            const int oc = idx >> 6;
            pre[(size_t)(t0 * DOUT_ + o0 * 256 + c * 16 + oc) * 64 + b] = trans[oc][b];
        }
    }
}

// -----------------------------------------------------------------------------
// Scan: one wave per o, lane = b. Batch-mean via ballot+popcount.
// Software-pipelined 16-deep load batches (two NAMED arrays -> registers,
// never runtime-indexed): batch t+16 issues before batch t's serial
// ballot-chain runs, hiding ~900 cyc HBM latency under ~800 cyc of compute.
// -----------------------------------------------------------------------------
#define SCAN_LOAD(PV, TB)                                                      \
    do {                                                                       \
        _Pragma("unroll")                                                      \
        for (int j = 0; j < 16; ++j)                                           \
            PV[j] = p[(size_t)((TB) + j) * (DOUT_ * 64)];                      \
    } while (0)

#define SCAN_STEP(PV, TB)                                                      \
    do {                                                                       \
        _Pragma("unroll")                                                      \
        for (int j = 0; j < 16; ++j) {                                         \
            mem += PV[j];                                                      \
            const bool s = (mem >= thr);                                       \
            const unsigned long long msk = __ballot(s);                        \
            thr += 0.05 * ((double)__popcll(msk) * (1.0 / 64.0) - 0.5);        \
            if (spM) {                                                         \
                if (lane == 0) spM[(size_t)((TB) + j) * DOUT_ + o] = msk;      \
            } else {                                                           \
                outD[(size_t)lane * (T_ * DOUT_) +                             \
                     (size_t)((TB) + j) * DOUT_ + o] = s ? 1.0f : 0.0f;        \
            }                                                                  \
            mem = s ? 0.0 : mem;                                               \
        }                                                                      \
    } while (0)

__global__ __launch_bounds__(256) void snn_scan(
    const double* __restrict__ pre, const float* __restrict__ thr_in,
    unsigned long long* __restrict__ spM, float* __restrict__ outD)
{
    const int wid  = (blockIdx.x * blockDim.x + threadIdx.x) >> 6;
    const int lane = threadIdx.x & 63;
    if (wid >= DOUT_) return;
    const int o = wid;

    double mem = 0.0;
    double thr = (double)thr_in[o];
    const double* p = pre + (size_t)o * 64 + lane;

    double pvA[16], pvB[16];
    SCAN_LOAD(pvA, 0);
    for (int t = 0; t < T_; t += 32) {
        if (t + 16 < T_) SCAN_LOAD(pvB, t + 16);
        SCAN_STEP(pvA, t);
        if (t + 32 < T_) SCAN_LOAD(pvA, t + 32);
        SCAN_STEP(pvB, t + 16);
    }
}

// -----------------------------------------------------------------------------
// Expand: thread = (t, o-group-of-4). Reads 4 masks (32B/lane contiguous),
// writes float4 per b (16B/lane, 1KB/wave contiguous stores).
// -----------------------------------------------------------------------------
__global__ __launch_bounds__(256) void snn_expand(
    const unsigned long long* __restrict__ spM, float* __restrict__ out)
{
    const int idx = blockIdx.x * 256 + threadIdx.x;  // 0..65535
    const int og = idx & 255;                        // o/4
    const int t  = idx >> 8;
    const unsigned long long* mp = spM + (size_t)t * DOUT_ + og * 4;
    const unsigned long long m0 = mp[0], m1 = mp[1], m2 = mp[2], m3 = mp[3];
    float* op = out + (size_t)t * DOUT_ + og * 4;
#pragma unroll
    for (int b = 0; b < 64; ++b) {
        float4 v;
        v.x = (float)((m0 >> b) & 1ULL);
        v.y = (float)((m1 >> b) & 1ULL);
        v.z = (float)((m2 >> b) & 1ULL);
        v.w = (float)((m3 >> b) & 1ULL);
        *(float4*)(op + (size_t)b * (T_ * DOUT_)) = v;
    }
}

extern "C" void kernel_launch(void* const* d_in, const int* in_sizes, int n_in,
                              void* d_out, int out_size, void* d_ws, size_t ws_size,
                              hipStream_t stream) {
    const float* x    = (const float*)d_in[0];   // [64][256][1024]
    const float* W    = (const float*)d_in[1];   // [1024][1024]
    const float* bias = (const float*)d_in[2];   // [1024]
    const float* thr  = (const float*)d_in[3];   // [1024]
    float* out = (float*)d_out;                  // [64][256][1024]

    double* pre = (double*)d_ws;
    const size_t need = PRE_BYTES + XS_BYTES + WSL_BYTES + SPM_BYTES;

    if (ws_size >= need) {
        char* xs  = (char*)d_ws + PRE_BYTES;
        char* wsl = xs + XS_BYTES;
        unsigned long long* spM = (unsigned long long*)(wsl + WSL_BYTES);
        snn_split_x<<<4096, 256, 0, stream>>>(x, xs);
        snn_split_w<<<256, 256, 0, stream>>>(W, wsl);
        snn_gemm_i8<<<4096, 256, 0, stream>>>(xs, wsl, bias, pre);
        snn_scan<<<256, 256, 0, stream>>>(pre, thr, spM, nullptr);
        snn_expand<<<256, 256, 0, stream>>>(spM, out);
    } else {
        const bool two_stage = (ws_size >= PRE_BYTES + SPM_BYTES);
        unsigned long long* spM =
            two_stage ? (unsigned long long*)((char*)d_ws + PRE_BYTES) : nullptr;
        snn_gemm_fb<<<1024, 256, 0, stream>>>(x, W, bias, pre);
        snn_scan<<<256, 256, 0, stream>>>(pre, thr, spM, two_stage ? nullptr : out);
        if (two_stage)
            snn_expand<<<1024, 256, 0, stream>>>(spM, out);
    }
}